// Round 2
// baseline (528.491 us; speedup 1.0000x reference)
//
#include <hip/hip_runtime.h>
#include <math.h>

#define CIN 256
#define COUT 64
#define KN 1024
#define PN 80000
#define SIMT 0.9f

typedef __attribute__((ext_vector_type(8))) short  short8;   // 8 bf16 = 4 VGPRs
typedef __attribute__((ext_vector_type(4))) float  f32x4;    // MFMA acc

// fp32 -> bf16 round-to-nearest-even (bit pattern)
__device__ inline unsigned short f2bf(float f) {
    unsigned u = __float_as_uint(f);
    unsigned r = u + 0x7FFFu + ((u >> 16) & 1u);
    return (unsigned short)(r >> 16);
}

// ---------------------------------------------------------------------------
// Kernel A: mw = feat^T @ W^T + b  (1024x64), then a = row-normalize(mw).
// One wave (64 lanes) per k-row; lane = o.
// ---------------------------------------------------------------------------
__global__ __launch_bounds__(256) void k_mw(const float* __restrict__ idx_feat,
                                            const float* __restrict__ W,
                                            const float* __restrict__ b,
                                            float* __restrict__ mw,
                                            float* __restrict__ a) {
    int t = threadIdx.x;
    int id = blockIdx.x * 256 + t;
    int k = id >> 6;      // wave-uniform (64 threads per k)
    int o = id & 63;
    const float4* W4 = (const float4*)W;
    float acc = 0.f;
    #pragma unroll 4
    for (int c4 = 0; c4 < 64; ++c4) {
        float4 wv = W4[o * 64 + c4];
        int c = c4 * 4;
        acc += idx_feat[(c + 0) * KN + k] * wv.x
             + idx_feat[(c + 1) * KN + k] * wv.y
             + idx_feat[(c + 2) * KN + k] * wv.z
             + idx_feat[(c + 3) * KN + k] * wv.w;
    }
    float v = acc + b[o];
    mw[k * COUT + o] = v;
    float ss = v * v;
    #pragma unroll
    for (int m = 1; m < 64; m <<= 1) ss += __shfl_xor(ss, m, 64);
    float nrm = sqrtf(ss);
    a[k * COUT + o] = v / fmaxf(nrm, 1e-8f);
}

// ---------------------------------------------------------------------------
// Kernel B: per column j: sim[i,j], label = triu & (sim>=0.9) & cate-match,
// column-wise prefix count < 2 (cum), keep[j] = cum[j,j],
// packed bitmask of (label & cum) per column -> mask[j*32 + w].
// ---------------------------------------------------------------------------
__global__ __launch_bounds__(256) void k_label(const float* __restrict__ a,
                                               const int* __restrict__ cate,
                                               unsigned int* __restrict__ mask,
                                               unsigned int* __restrict__ keep) {
    int j = blockIdx.x;
    int t = threadIdx.x;
    __shared__ __align__(16) float ajs[64];
    __shared__ int cnts[256];
    __shared__ unsigned int mws[32];
    if (t < 64) ajs[t] = a[j * 64 + t];
    if (t < 32) mws[t] = 0u;
    __syncthreads();
    int cj = cate[j];
    const float4* a4  = (const float4*)a;
    const float4* aj4 = (const float4*)ajs;
    bool lab[4];
    int cnt = 0;
    #pragma unroll
    for (int q = 0; q < 4; ++q) {
        int i = t * 4 + q;
        float s = 0.f;
        #pragma unroll
        for (int c4 = 0; c4 < 16; ++c4) {
            float4 av = a4[i * 16 + c4];
            float4 jv = aj4[c4];
            s += av.x * jv.x + av.y * jv.y + av.z * jv.z + av.w * jv.w;
        }
        lab[q] = (i <= j) && (s >= SIMT) && (cate[i] == cj);
        cnt += lab[q] ? 1 : 0;
    }
    cnts[t] = cnt;
    __syncthreads();
    for (int off = 1; off < 256; off <<= 1) {
        int v = cnts[t];
        int add = (t >= off) ? cnts[t - off] : 0;
        __syncthreads();
        cnts[t] = v + add;
        __syncthreads();
    }
    int run = cnts[t] - cnt;
    #pragma unroll
    for (int q = 0; q < 4; ++q) {
        int i = t * 4 + q;
        run += lab[q] ? 1 : 0;
        bool cumf = run < 2;
        if (lab[q] && cumf) atomicOr(&mws[i >> 5], 1u << (i & 31));
        if (i == j) keep[j] = cumf ? 1u : 0u;
    }
    __syncthreads();
    if (t < 32) mask[j * 32 + t] = mws[t];
}

// ---------------------------------------------------------------------------
// Kernel C: merged[i,c] = keep[i] * sum_j lm[i,j]*mw[j,c] / max(cnt,1).
// One block per row i. Output: bf16 row-major mergedB[i*64+c] for MFMA B-frags.
// ---------------------------------------------------------------------------
__global__ __launch_bounds__(256) void k_merge(const float* __restrict__ mw,
                                               const unsigned int* __restrict__ mask,
                                               const unsigned int* __restrict__ keep,
                                               unsigned short* __restrict__ mergedB) {
    int i = blockIdx.x;
    int t = threadIdx.x;
    int c = t & 63, g = t >> 6;
    int wi = i >> 5;
    unsigned int bi = 1u << (i & 31);
    float acc = 0.f;
    int cnt = 0;
    for (int jj = 0; jj < 256; ++jj) {
        int j = g * 256 + jj;
        unsigned int wv = mask[j * 32 + wi];   // wave-uniform
        if (wv & bi) { acc += mw[j * 64 + c]; cnt++; }
    }
    __shared__ float sa[4][64];
    __shared__ int sc[4];
    sa[g][c] = acc;
    if (c == 0) sc[g] = cnt;
    __syncthreads();
    if (g == 0) {
        float tot = sa[0][c] + sa[1][c] + sa[2][c] + sa[3][c];
        int ct = sc[0] + sc[1] + sc[2] + sc[3];
        float mv = keep[i] ? tot / (float)max(ct, 1) : 0.f;
        mergedB[i * 64 + c] = f2bf(mv);
    }
}

// ---------------------------------------------------------------------------
// Kernel D: inst[k,p] = sum_c merged[k,c] * x[c,p] via bf16 MFMA 16x16x32,
// OPERAND-SWAPPED: A = x-fragment (m = p-col), B = merged-fragment (n = k-row).
// Verified layouts (m89/m120): A[m=lane&15][kk=quad*8+j]; B[kk][n=lane&15];
// D: col(n)=lane&15, row(m)=quad*4+reg. With m=p, the reg index walks 4
// CONSECUTIVE p columns -> one aligned float4 store per lane per k-tile
// (16 rows x 64B = 1KB useful/instruction; 4x fewer store instrs than dword).
// Each wave owns 16 p-cols; x A-frags (fp32->bf16 in-register) loaded ONCE,
// reused over all 64 k-tiles. mergedB B-frags stream (128 KB, L2-resident).
// x read exactly once (grid.y eliminated). Tail outputs fused into block 0.
// ---------------------------------------------------------------------------
__global__ __launch_bounds__(256) void k_inst(const float* __restrict__ x,
                                              const unsigned short* __restrict__ mergedB,
                                              const int* __restrict__ cate,
                                              const float* __restrict__ score,
                                              const unsigned int* __restrict__ keep,
                                              float* __restrict__ out) {
    int t = threadIdx.x;
    int lane = t & 63;
    int wv = t >> 6;                        // wave id 0..3
    int l15 = lane & 15;
    int quad = lane >> 4;
    int p0 = blockIdx.x * 64 + wv * 16;     // this wave's p base
    int pp = p0 + l15;                      // this lane's p column (A m-index)

    // A fragments: x[c][pp] for c = quad*8+j (frag 0) and c = 32+quad*8+j
    // (frag 1), converted fp32->bf16. Same loads as the old kernel's B-frags.
    short8 a0, a1;
    #pragma unroll
    for (int j = 0; j < 8; ++j) {
        int c = quad * 8 + j;
        a0[j] = (short)f2bf(x[c * PN + pp]);
        a1[j] = (short)f2bf(x[(c + 32) * PN + pp]);
    }

    // Stream 64 k-tiles of 16 rows; B-frag = mergedB[k0+l15][quad*8+j (+32)].
    #pragma unroll 4
    for (int kt = 0; kt < 64; ++kt) {
        int k0 = kt * 16;
        const unsigned short* bp = mergedB + (k0 + l15) * 64 + quad * 8;
        short8 b0 = *(const short8*)(bp);        // c 0..31 octet
        short8 b1 = *(const short8*)(bp + 32);   // c 32..63 octet
        f32x4 acc = {0.f, 0.f, 0.f, 0.f};
        acc = __builtin_amdgcn_mfma_f32_16x16x32_bf16(a0, b0, acc, 0, 0, 0);
        acc = __builtin_amdgcn_mfma_f32_16x16x32_bf16(a1, b1, acc, 0, 0, 0);
        // D[m=quad*4+r][n=l15] = out[k0+l15][p0+quad*4+r] -> contiguous float4
        float4 v = {acc[0], acc[1], acc[2], acc[3]};
        *(float4*)(out + (k0 + l15) * PN + p0 + quad * 4) = v;
    }

    // Fused tail: keep (0/1), pred_cate (float), score.
    if (blockIdx.x == 0) {
        long base = (long)KN * PN;
        for (int i = t; i < KN; i += 256) {
            out[base + i]            = keep[i] ? 1.f : 0.f;
            out[base + KN + i]       = (float)cate[i];
            out[base + 2 * KN + i]   = score[i];
        }
    }
}

extern "C" void kernel_launch(void* const* d_in, const int* in_sizes, int n_in,
                              void* d_out, int out_size, void* d_ws, size_t ws_size,
                              hipStream_t stream) {
    // setup_inputs order: x, idx_feat, pred_cate, pred_score, W, b, n, h, w
    const float* x        = (const float*)d_in[0];   // (64, 80000)
    const float* idx_feat = (const float*)d_in[1];   // (256, 1024)
    const int*   cate     = (const int*)d_in[2];     // (1024,)
    const float* score    = (const float*)d_in[3];   // (1024,)
    const float* W        = (const float*)d_in[4];   // (64, 256)
    const float* b        = (const float*)d_in[5];   // (64,)
    float* out = (float*)d_out;

    char* ws = (char*)d_ws;
    float*          mw      = (float*)(ws + 0);            // 256 KB
    float*          a       = (float*)(ws + 262144);       // 256 KB
    unsigned short* mergedB = (unsigned short*)(ws + 524288); // 128 KB (bf16)
    unsigned int*   mask    = (unsigned int*)(ws + 655360); // 128 KB
    unsigned int*   keep    = (unsigned int*)(ws + 786432); // 4 KB

    k_mw   <<<256,  256, 0, stream>>>(idx_feat, W, b, mw, a);
    k_label<<<KN,   256, 0, stream>>>(a, cate, mask, keep);
    k_merge<<<KN,   256, 0, stream>>>(mw, mask, keep, mergedB);
    k_inst <<<PN / 64, 256, 0, stream>>>(x, mergedB, cate, score, keep, out);
}